// Round 7
// baseline (153.636 us; speedup 1.0000x reference)
//
#include <hip/hip_runtime.h>
#include <hip/hip_bf16.h>
#include <math.h>

// Problem constants (fixed by setup_inputs)
#define SS 1024
#define MM 512
#define LRC (0.1f/2048.0f)          // LR / (B*S)
#define SCALE 0.17677669529663687f  // 1/sqrt(32)
#define NBLK 256

typedef __attribute__((ext_vector_type(8))) short s8v;    // 8 bf16 (one MFMA frag)
typedef __attribute__((ext_vector_type(4))) float f32x4;
#define MFMA16(a, b, c) __builtin_amdgcn_mfma_f32_16x16x32_bf16(a, b, c, 0, 0, 0)

__device__ __forceinline__ unsigned short f2b(float f) {   // fp32 -> bf16 RNE
  union { float f; unsigned int u; } v; v.f = f;
  return (unsigned short)((v.u + 0x7FFFu + ((v.u >> 16) & 1u)) >> 16);
}

// Software grid barrier: 256 blocks all co-resident (grid == CU count).
// Device-scope atomics + __threadfence() give cross-XCD visibility (G16).
__device__ __forceinline__ void grid_barrier(int* bar) {
  __syncthreads();
  if (threadIdx.x == 0) {
    int* cnt = bar;
    int* gen = bar + 1;
    __threadfence();                               // release my block's writes
    const int g = __hip_atomic_load(gen, __ATOMIC_RELAXED, __HIP_MEMORY_SCOPE_AGENT);
    const int prev = __hip_atomic_fetch_add(cnt, 1, __ATOMIC_ACQ_REL, __HIP_MEMORY_SCOPE_AGENT);
    if (prev == NBLK - 1) {
      __hip_atomic_store(cnt, 0, __ATOMIC_RELAXED, __HIP_MEMORY_SCOPE_AGENT);
      __hip_atomic_store(gen, g + 1, __ATOMIC_RELEASE, __HIP_MEMORY_SCOPE_AGENT);
    } else {
      while (__hip_atomic_load(gen, __ATOMIC_ACQUIRE, __HIP_MEMORY_SCOPE_AGENT) == g) {
        __builtin_amdgcn_s_sleep(8);
      }
    }
    __threadfence();                               // acquire others' writes
  }
  __syncthreads();
}

// ---------------------------------------------------------------------------
// Single persistent kernel, 256 blocks x 256 threads, 3 phases (R6 bodies).
// ---------------------------------------------------------------------------
__global__ __launch_bounds__(256) void k_mega(
    const float* __restrict__ x, const float* __restrict__ mem,
    const float* __restrict__ wq, const float* __restrict__ wk,
    const float* __restrict__ wv, const float* __restrict__ wo,
    const float* __restrict__ wfc,
    const float* __restrict__ bq, const float* __restrict__ bk,
    const float* __restrict__ bv, const float* __restrict__ bo,
    const float* __restrict__ bfc,
    unsigned short* __restrict__ STb, unsigned short* __restrict__ xT,
    unsigned short* __restrict__ qbf, unsigned short* __restrict__ kbf,
    unsigned short* __restrict__ vT,
    unsigned short* __restrict__ wkb, unsigned short* __restrict__ wvb,
    unsigned short* __restrict__ wob, unsigned short* __restrict__ wfcb,
    int* __restrict__ bar, float* __restrict__ out) {
  __shared__ alignas(16) char smem[75264];
  const int t = threadIdx.x, bx = blockIdx.x;
  const int w = t >> 6, l = t & 63;
  const int kq = (l >> 4) * 8;
  const int r0l = (l >> 4) * 4;

  // ================= P1: surprise tiles (all 256 blocks) =================
  {
    float (*xl)[132]          = reinterpret_cast<float (*)[132]>(smem);
    unsigned short (*xb)[136] = reinterpret_cast<unsigned short (*)[136]>(smem + 33792);
    unsigned short (*mb)[136] = reinterpret_cast<unsigned short (*)[136]>(smem + 51200);
    float* xn                 = reinterpret_cast<float*>(smem + 68608);
    float* mn                 = reinterpret_cast<float*>(smem + 68864);
    const int bs0 = (bx & 31) * 64, m0 = (bx >> 5) * 64;

    for (int i = t; i < 2048; i += 256) {          // stage x tile (fp32 + bf16)
      int r = i >> 5, c4 = (i & 31) * 4;
      float4 v = *reinterpret_cast<const float4*>(&x[(bs0 + r) * 128 + c4]);
      xl[r][c4] = v.x; xl[r][c4+1] = v.y; xl[r][c4+2] = v.z; xl[r][c4+3] = v.w;
      ushort4 u; u.x = f2b(v.x); u.y = f2b(v.y); u.z = f2b(v.z); u.w = f2b(v.w);
      *reinterpret_cast<ushort4*>(&xb[r][c4]) = u;
    }
    __syncthreads();
    {                                              // xnorm (fp32)
      int r = t >> 2, q = t & 3;
      float s = 0.f;
      #pragma unroll
      for (int j = 0; j < 32; ++j) { float v = xl[r][q * 32 + j]; s += v * v; }
      s += __shfl_xor(s, 1); s += __shfl_xor(s, 2);
      if (q == 0) xn[r] = s;
    }
    if ((bx >> 5) == 0) {                          // emit xT for P2
      int d = t >> 1, hh = t & 1;
      #pragma unroll
      for (int j4 = 0; j4 < 32; j4 += 4) {
        ushort4 u;
        u.x = xb[hh*32 + j4    ][d];
        u.y = xb[hh*32 + j4 + 1][d];
        u.z = xb[hh*32 + j4 + 2][d];
        u.w = xb[hh*32 + j4 + 3][d];
        *reinterpret_cast<ushort4*>(&xT[d * 2048 + bs0 + hh*32 + j4]) = u;
      }
    }
    __syncthreads();                               // xl free -> reuse for mem
    for (int i = t; i < 2048; i += 256) {
      int r = i >> 5, c4 = (i & 31) * 4;
      float4 v = *reinterpret_cast<const float4*>(&mem[(m0 + r) * 128 + c4]);
      xl[r][c4] = v.x; xl[r][c4+1] = v.y; xl[r][c4+2] = v.z; xl[r][c4+3] = v.w;
      ushort4 u; u.x = f2b(v.x); u.y = f2b(v.y); u.z = f2b(v.z); u.w = f2b(v.w);
      *reinterpret_cast<ushort4*>(&mb[r][c4]) = u;
    }
    __syncthreads();
    {                                              // mnorm (fp32)
      int r = t >> 2, q = t & 3;
      float s = 0.f;
      #pragma unroll
      for (int j = 0; j < 32; ++j) { float v = xl[r][q * 32 + j]; s += v * v; }
      s += __shfl_xor(s, 1); s += __shfl_xor(s, 2);
      if (q == 0) mn[r] = s;
    }
    __syncthreads();
    f32x4 acc[4] = {};                             // G = x@mem^T
    #pragma unroll
    for (int kc = 0; kc < 4; ++kc) {
      s8v a = *reinterpret_cast<const s8v*>(&xb[w*16 + (l&15)][kc*32 + kq]);
      #pragma unroll
      for (int mt = 0; mt < 4; ++mt) {
        s8v b = *reinterpret_cast<const s8v*>(&mb[mt*16 + (l&15)][kc*32 + kq]);
        acc[mt] = MFMA16(a, b, acc[mt]);
      }
    }
    const int r0g = bs0 + w * 16 + r0l;
    float xnr[4];
    #pragma unroll
    for (int i = 0; i < 4; ++i) xnr[i] = xn[w*16 + r0l + i];
    #pragma unroll
    for (int mt = 0; mt < 4; ++mt) {
      const int coll = mt * 16 + (l & 15);
      const float mnv = mn[coll];
      ushort4 u;
      u.x = f2b(sqrtf(fmaxf(0.f, xnr[0] + mnv - 2.f * acc[mt][0])));
      u.y = f2b(sqrtf(fmaxf(0.f, xnr[1] + mnv - 2.f * acc[mt][1])));
      u.z = f2b(sqrtf(fmaxf(0.f, xnr[2] + mnv - 2.f * acc[mt][2])));
      u.w = f2b(sqrtf(fmaxf(0.f, xnr[3] + mnv - 2.f * acc[mt][3])));
      *reinterpret_cast<ushort4*>(&STb[(m0 + coll) * 2048 + r0g]) = u;
    }
    if (bx >= 249) {                               // weight conversion epilogue
      const float* src; unsigned short* dst; int off = 0;
      if (bx == 249)      { src = wk;  dst = wkb; }
      else if (bx == 250) { src = wv;  dst = wvb; }
      else if (bx == 251) { src = wo;  dst = wob; }
      else                { src = wfc; dst = wfcb; off = (bx - 252) * 16384; }
      for (int i = t; i < 4096; i += 256) {
        float4 v = *reinterpret_cast<const float4*>(&src[off + i * 4]);
        ushort4 u; u.x = f2b(v.x); u.y = f2b(v.y); u.z = f2b(v.z); u.w = f2b(v.w);
        *reinterpret_cast<ushort4*>(&dst[off + i * 4]) = u;
      }
    }
  }
  grid_barrier(bar);

  // ====== P2: kv strips (bx<32) and q projection (32<=bx<64) ======
  if (bx < 32) {
    float (*Tld)[132] = reinterpret_cast<float (*)[132]>(smem);
    float* srowl      = reinterpret_cast<float*>(smem + 8448);
    unsigned short (*mnl)[136] = reinterpret_cast<unsigned short (*)[136]>(smem + 8512);
    const int m0 = bx * 16;
    f32x4 acc[2] = {};
    float ssum = 0.f;
    const int arow = m0 + (l & 15);
    #pragma unroll 4
    for (int kk = 0; kk < 64; ++kk) {
      s8v a = *reinterpret_cast<const s8v*>(&STb[arow * 2048 + kk * 32 + kq]);
      #pragma unroll
      for (int j = 0; j < 8; ++j) {    // srow partial from streamed S values
        union { unsigned int u; float f; } cv;
        cv.u = ((unsigned int)(unsigned short)a[j]) << 16;
        ssum += cv.f;
      }
      #pragma unroll
      for (int nt = 0; nt < 2; ++nt) {
        s8v b = *reinterpret_cast<const s8v*>(&xT[(w*32 + nt*16 + (l&15)) * 2048 + kk*32 + kq]);
        acc[nt] = MFMA16(a, b, acc[nt]);
      }
    }
    ssum += __shfl_xor(ssum, 16); ssum += __shfl_xor(ssum, 32);
    if (w == 0 && l < 16) srowl[l] = ssum;
    #pragma unroll
    for (int nt = 0; nt < 2; ++nt) {
      const int col = w * 32 + nt * 16 + (l & 15);
      #pragma unroll
      for (int i = 0; i < 4; ++i) Tld[r0l + i][col] = acc[nt][i];
    }
    __syncthreads();
    #pragma unroll
    for (int i = 0; i < 8; ++i) {      // memn strip (bf16, LDS only)
      const int flat = t + 256 * i;
      const int r = flat >> 7, c = flat & 127;
      const float mv = mem[(m0 + r) * 128 + c];
      mnl[r][c] = f2b(mv + LRC * (Tld[r][c] - srowl[r] * mv));
    }
    __syncthreads();
    #pragma unroll
    for (int p = 0; p < 2; ++p) {      // p=0: k, p=1: v
      const unsigned short* W = p ? wvb : wkb;
      const float* bias = p ? bv : bk;
      f32x4 pacc[2] = {};
      #pragma unroll
      for (int kc = 0; kc < 4; ++kc) {
        s8v a = *reinterpret_cast<const s8v*>(&mnl[l & 15][kc * 32 + kq]);
        #pragma unroll
        for (int nt = 0; nt < 2; ++nt) {
          s8v b = *reinterpret_cast<const s8v*>(&W[(w*32 + nt*16 + (l&15)) * 128 + kc*32 + kq]);
          pacc[nt] = MFMA16(a, b, pacc[nt]);
        }
      }
      #pragma unroll
      for (int nt = 0; nt < 2; ++nt) {
        const int col = w * 32 + nt * 16 + (l & 15);
        const float bb = bias[col];
        if (p == 0) {
          #pragma unroll
          for (int i = 0; i < 4; ++i)
            kbf[(m0 + r0l + i) * 128 + col] = f2b(pacc[nt][i] + bb);
        } else {
          ushort4 u;
          u.x = f2b(pacc[nt][0] + bb); u.y = f2b(pacc[nt][1] + bb);
          u.z = f2b(pacc[nt][2] + bb); u.w = f2b(pacc[nt][3] + bb);
          *reinterpret_cast<ushort4*>(&vT[col * 512 + m0 + r0l]) = u;
        }
      }
    }
  } else if (bx < 64) {                // ---- q projection ----
    unsigned short (*xb)[136]  = reinterpret_cast<unsigned short (*)[136]>(smem);
    unsigned short (*wql)[136] = reinterpret_cast<unsigned short (*)[136]>(smem + 17408);
    const int s0 = (bx - 32) * 64;
    for (int i = t; i < 2048; i += 256) {
      int r = i >> 5, c4 = (i & 31) * 4;
      float4 v = *reinterpret_cast<const float4*>(&x[(s0 + r) * 128 + c4]);
      ushort4 u; u.x = f2b(v.x); u.y = f2b(v.y); u.z = f2b(v.z); u.w = f2b(v.w);
      *reinterpret_cast<ushort4*>(&xb[r][c4]) = u;
    }
    for (int i = t; i < 4096; i += 256) {
      int r = i >> 5, c4 = (i & 31) * 4;
      float4 v = *reinterpret_cast<const float4*>(&wq[r * 128 + c4]);
      ushort4 u; u.x = f2b(v.x); u.y = f2b(v.y); u.z = f2b(v.z); u.w = f2b(v.w);
      *reinterpret_cast<ushort4*>(&wql[r][c4]) = u;
    }
    __syncthreads();
    f32x4 acc[8] = {};
    #pragma unroll
    for (int kc = 0; kc < 4; ++kc) {
      s8v a = *reinterpret_cast<const s8v*>(&xb[w*16 + (l&15)][kc*32 + kq]);
      #pragma unroll
      for (int nt = 0; nt < 8; ++nt) {
        s8v b = *reinterpret_cast<const s8v*>(&wql[nt*16 + (l&15)][kc*32 + kq]);
        acc[nt] = MFMA16(a, b, acc[nt]);
      }
    }
    const int r0g = s0 + w * 16 + r0l;
    #pragma unroll
    for (int nt = 0; nt < 8; ++nt) {
      const int col = nt * 16 + (l & 15);
      const float bb = bq[col];
      #pragma unroll
      for (int i = 0; i < 4; ++i)
        qbf[(r0g + i) * 128 + col] = f2b((acc[nt][i] + bb) * SCALE);
    }
  }
  grid_barrier(bar);

  // ================= P3: attention + wo + fc (bx<128) =================
  if (bx < 128) {
    unsigned short (*Pl)[520] = reinterpret_cast<unsigned short (*)[520]>(smem);
    unsigned short (*cl)[136] = reinterpret_cast<unsigned short (*)[136]>(smem + 66560);
    unsigned short (*al)[136] = reinterpret_cast<unsigned short (*)[136]>(smem + 70912);
    const int r0 = bx * 16;            // 16 query rows (bs index)

    {                                  // -- phase A: scores + softmax, head w --
      const int h = w;
      const s8v a = *reinterpret_cast<const s8v*>(&qbf[(r0 + (l & 15)) * 128 + h * 32 + kq]);
      f32x4 acc[32];
      #pragma unroll
      for (int mt = 0; mt < 32; ++mt) acc[mt] = f32x4{0.f, 0.f, 0.f, 0.f};
      #pragma unroll
      for (int mt = 0; mt < 32; ++mt) {
        s8v b2 = *reinterpret_cast<const s8v*>(&kbf[(mt*16 + (l&15)) * 128 + h*32 + kq]);
        acc[mt] = MFMA16(a, b2, acc[mt]);
      }
      #pragma unroll
      for (int i = 0; i < 4; ++i) {
        float mx = acc[0][i];
        #pragma unroll
        for (int mt = 1; mt < 32; ++mt) mx = fmaxf(mx, acc[mt][i]);
        mx = fmaxf(mx, __shfl_xor(mx, 1));
        mx = fmaxf(mx, __shfl_xor(mx, 2));
        mx = fmaxf(mx, __shfl_xor(mx, 4));
        mx = fmaxf(mx, __shfl_xor(mx, 8));
        float sm = 0.f;
        #pragma unroll
        for (int mt = 0; mt < 32; ++mt) {
          float e = __expf(acc[mt][i] - mx); acc[mt][i] = e; sm += e;
        }
        sm += __shfl_xor(sm, 1); sm += __shfl_xor(sm, 2);
        sm += __shfl_xor(sm, 4); sm += __shfl_xor(sm, 8);
        const float inv = 1.f / sm;
        #pragma unroll
        for (int mt = 0; mt < 32; ++mt)
          Pl[h * 16 + r0l + i][mt * 16 + (l & 15)] = f2b(acc[mt][i] * inv);
      }
    }
    __syncthreads();
    {                                  // -- phase B: PV, head w --
      const int h = w;
      f32x4 acc[2] = {};
      #pragma unroll 4
      for (int kk = 0; kk < 16; ++kk) {
        s8v a = *reinterpret_cast<const s8v*>(&Pl[h * 16 + (l & 15)][kk * 32 + kq]);
        #pragma unroll
        for (int nt = 0; nt < 2; ++nt) {
          s8v b2 = *reinterpret_cast<const s8v*>(&vT[(h*32 + nt*16 + (l&15)) * 512 + kk*32 + kq]);
          acc[nt] = MFMA16(a, b2, acc[nt]);
        }
      }
      #pragma unroll
      for (int nt = 0; nt < 2; ++nt) {
        const int col = h * 32 + nt * 16 + (l & 15);
        #pragma unroll
        for (int i = 0; i < 4; ++i) cl[r0l + i][col] = f2b(acc[nt][i]);
      }
    }
    __syncthreads();
    {                                  // -- phase C: attno = ctx@wo^T + bo --
      f32x4 acc[2] = {};
      #pragma unroll
      for (int kc = 0; kc < 4; ++kc) {
        s8v a = *reinterpret_cast<const s8v*>(&cl[l & 15][kc * 32 + kq]);
        #pragma unroll
        for (int nt = 0; nt < 2; ++nt) {
          s8v b2 = *reinterpret_cast<const s8v*>(&wob[(w*32 + nt*16 + (l&15)) * 128 + kc*32 + kq]);
          acc[nt] = MFMA16(a, b2, acc[nt]);
        }
      }
      #pragma unroll
      for (int nt = 0; nt < 2; ++nt) {
        const int col = w * 32 + nt * 16 + (l & 15);
        const float bb = bo[col];
        #pragma unroll
        for (int i = 0; i < 4; ++i) al[r0l + i][col] = f2b(acc[nt][i] + bb);
      }
    }
    __syncthreads();
    {                                  // -- phase D: out = relu(attno@wfc^T + bfc) --
      f32x4 acc[8] = {};
      #pragma unroll
      for (int kc = 0; kc < 4; ++kc) {
        s8v a = *reinterpret_cast<const s8v*>(&al[l & 15][kc * 32 + kq]);
        #pragma unroll
        for (int nt = 0; nt < 8; ++nt) {
          s8v b2 = *reinterpret_cast<const s8v*>(&wfcb[(w*128 + nt*16 + (l&15)) * 128 + kc*32 + kq]);
          acc[nt] = MFMA16(a, b2, acc[nt]);
        }
      }
      #pragma unroll
      for (int nt = 0; nt < 8; ++nt) {
        const int col = w * 128 + nt * 16 + (l & 15);
        const float bb = bfc[col];
        #pragma unroll
        for (int i = 0; i < 4; ++i)
          out[(r0 + r0l + i) * 512 + col] = fmaxf(acc[nt][i] + bb, 0.f);
      }
    }
  }
}

// ---------------------------------------------------------------------------
extern "C" void kernel_launch(void* const* d_in, const int* in_sizes, int n_in,
                              void* d_out, int out_size, void* d_ws, size_t ws_size,
                              hipStream_t stream) {
  const float* x    = (const float*)d_in[0];
  const float* mem  = (const float*)d_in[1];
  const float* w_q  = (const float*)d_in[2];
  const float* w_k  = (const float*)d_in[3];
  const float* w_v  = (const float*)d_in[4];
  const float* b_q  = (const float*)d_in[5];
  const float* b_k  = (const float*)d_in[6];
  const float* b_v  = (const float*)d_in[7];
  const float* w_o  = (const float*)d_in[8];
  const float* b_o  = (const float*)d_in[9];
  const float* w_fc = (const float*)d_in[10];
  const float* b_fc = (const float*)d_in[11];
  float* out = (float*)d_out;

  char* base = (char*)d_ws;            // ~3.65 MB total
  unsigned short* STb  = (unsigned short*)(base);             // 2 MB   S^T[m][bs]
  unsigned short* xT   = (unsigned short*)(base + 2097152);   // 512 KB x^T[d][bs]
  unsigned short* qbf  = (unsigned short*)(base + 2621440);   // 512 KB
  unsigned short* kbf  = (unsigned short*)(base + 3145728);   // 128 KB
  unsigned short* vT   = (unsigned short*)(base + 3276800);   // 128 KB v^T[d][m]
  unsigned short* wkb  = (unsigned short*)(base + 3407872);   // 32 KB
  unsigned short* wvb  = (unsigned short*)(base + 3440640);   // 32 KB
  unsigned short* wob  = (unsigned short*)(base + 3473408);   // 32 KB
  unsigned short* wfcb = (unsigned short*)(base + 3506176);   // 128 KB
  int* bar             = (int*)(base + 3637248);              // 8 B barrier state

  hipMemsetAsync(bar, 0, 8, stream);
  k_mega<<<NBLK, 256, 0, stream>>>(x, mem, w_q, w_k, w_v, w_o, w_fc,
                                   b_q, b_k, b_v, b_o, b_fc,
                                   STb, xT, qbf, kbf, vT,
                                   wkb, wvb, wob, wfcb, bar, out);
}

// Round 8
// 65.031 us; speedup vs baseline: 2.3625x; 2.3625x over previous
//
#include <hip/hip_runtime.h>
#include <hip/hip_bf16.h>
#include <math.h>

// Problem constants (fixed by setup_inputs)
#define SS 1024
#define MM 512
#define LRC (0.1f/2048.0f)          // LR / (B*S)
#define SCALE 0.17677669529663687f  // 1/sqrt(32)

typedef __attribute__((ext_vector_type(8))) short s8v;    // 8 bf16 (one MFMA frag)
typedef __attribute__((ext_vector_type(4))) float f32x4;
#define MFMA16(a, b, c) __builtin_amdgcn_mfma_f32_16x16x32_bf16(a, b, c, 0, 0, 0)

__device__ __forceinline__ unsigned short f2b(float f) {   // fp32 -> bf16 RNE
  union { float f; unsigned int u; } v; v.f = f;
  return (unsigned short)((v.u + 0x7FFFu + ((v.u >> 16) & 1u)) >> 16);
}

// ---------------------------------------------------------------------------
// D1 k_p1 (295 blocks):
//  bx<256   : surprise tile (bs0=(bx&31)*64, m0=(bx>>5)*64): fused
//             load+bf16-cvt+norm (no fp32 LDS); MFMA G=x@mem^T;
//             S=sqrt(xn+mn-2G) -> STb[m][bs]; per-tile column sums -> srowp.
//             m-row-0 blocks also emit xT[d][bs].
//  256..287 : q-projection (64 rows each): q=(x@wq^T+bq)*SCALE
//  288..294 : weight conversion wk,wv,wo,wfc -> bf16
// ---------------------------------------------------------------------------
__global__ __launch_bounds__(256) void k_p1(
    const float* __restrict__ x, const float* __restrict__ mem,
    const float* __restrict__ wq, const float* __restrict__ wk,
    const float* __restrict__ wv, const float* __restrict__ wo,
    const float* __restrict__ wfc, const float* __restrict__ bq,
    unsigned short* __restrict__ STb, unsigned short* __restrict__ xT,
    unsigned short* __restrict__ qbf, float* __restrict__ srowp,
    unsigned short* __restrict__ wkb, unsigned short* __restrict__ wvb,
    unsigned short* __restrict__ wob, unsigned short* __restrict__ wfcb) {
  __shared__ alignas(16) char smem[52224];
  const int t = threadIdx.x, bx = blockIdx.x;
  const int w = t >> 6, l = t & 63;
  const int kq = (l >> 4) * 8;
  const int r0l = (l >> 4) * 4;

  if (bx < 256) {                      // ======== surprise tiles ========
    unsigned short (*xb)[136] = reinterpret_cast<unsigned short (*)[136]>(smem);
    unsigned short (*mb)[136] = reinterpret_cast<unsigned short (*)[136]>(smem + 17408);
    float* xn                 = reinterpret_cast<float*>(smem + 34816);
    float* mn                 = reinterpret_cast<float*>(smem + 35072);
    float (*red)[64]          = reinterpret_cast<float (*)[64]>(smem + 35328);
    const int bs0 = (bx & 31) * 64, m0 = (bx >> 5) * 64;

    {                                  // fused load + bf16 cvt + row norms
      const int r = t >> 2, q = t & 3;
      const float* xp = &x[(bs0 + r) * 128 + q * 32];
      float s = 0.f;
      #pragma unroll
      for (int j4 = 0; j4 < 32; j4 += 4) {
        float4 v = *reinterpret_cast<const float4*>(xp + j4);
        s += v.x*v.x + v.y*v.y + v.z*v.z + v.w*v.w;
        ushort4 u; u.x = f2b(v.x); u.y = f2b(v.y); u.z = f2b(v.z); u.w = f2b(v.w);
        *reinterpret_cast<ushort4*>(&xb[r][q*32 + j4]) = u;
      }
      s += __shfl_xor(s, 1); s += __shfl_xor(s, 2);
      if (q == 0) xn[r] = s;
      const float* mp = &mem[(m0 + r) * 128 + q * 32];
      float sm_ = 0.f;
      #pragma unroll
      for (int j4 = 0; j4 < 32; j4 += 4) {
        float4 v = *reinterpret_cast<const float4*>(mp + j4);
        sm_ += v.x*v.x + v.y*v.y + v.z*v.z + v.w*v.w;
        ushort4 u; u.x = f2b(v.x); u.y = f2b(v.y); u.z = f2b(v.z); u.w = f2b(v.w);
        *reinterpret_cast<ushort4*>(&mb[r][q*32 + j4]) = u;
      }
      sm_ += __shfl_xor(sm_, 1); sm_ += __shfl_xor(sm_, 2);
      if (q == 0) mn[r] = sm_;
    }
    __syncthreads();
    if ((bx >> 5) == 0) {              // emit xT for P2
      int d = t >> 1, hh = t & 1;
      #pragma unroll
      for (int j4 = 0; j4 < 32; j4 += 4) {
        ushort4 u;
        u.x = xb[hh*32 + j4    ][d];
        u.y = xb[hh*32 + j4 + 1][d];
        u.z = xb[hh*32 + j4 + 2][d];
        u.w = xb[hh*32 + j4 + 3][d];
        *reinterpret_cast<ushort4*>(&xT[d * 2048 + bs0 + hh*32 + j4]) = u;
      }
    }
    f32x4 acc[4] = {};                 // G = x@mem^T
    #pragma unroll
    for (int kc = 0; kc < 4; ++kc) {
      s8v a = *reinterpret_cast<const s8v*>(&xb[w*16 + (l&15)][kc*32 + kq]);
      #pragma unroll
      for (int mt = 0; mt < 4; ++mt) {
        s8v b = *reinterpret_cast<const s8v*>(&mb[mt*16 + (l&15)][kc*32 + kq]);
        acc[mt] = MFMA16(a, b, acc[mt]);
      }
    }
    const int r0g = bs0 + w * 16 + r0l;
    float xnr[4];
    #pragma unroll
    for (int i = 0; i < 4; ++i) xnr[i] = xn[w*16 + r0l + i];
    #pragma unroll
    for (int mt = 0; mt < 4; ++mt) {
      const int coll = mt * 16 + (l & 15);
      const float mnv = mn[coll];
      const float s0 = sqrtf(fmaxf(0.f, xnr[0] + mnv - 2.f * acc[mt][0]));
      const float s1 = sqrtf(fmaxf(0.f, xnr[1] + mnv - 2.f * acc[mt][1]));
      const float s2 = sqrtf(fmaxf(0.f, xnr[2] + mnv - 2.f * acc[mt][2]));
      const float s3 = sqrtf(fmaxf(0.f, xnr[3] + mnv - 2.f * acc[mt][3]));
      ushort4 u; u.x = f2b(s0); u.y = f2b(s1); u.z = f2b(s2); u.w = f2b(s3);
      *reinterpret_cast<ushort4*>(&STb[(m0 + coll) * 2048 + r0g]) = u;
      float cs = s0 + s1 + s2 + s3;    // column partial over this wave's 16 rows
      cs += __shfl_xor(cs, 16); cs += __shfl_xor(cs, 32);
      if (l < 16) red[w][mt*16 + l] = cs;
    }
    __syncthreads();
    if (t < 64)                        // per-tile column sums -> srowp
      srowp[(bx & 31) * 512 + m0 + t] =
          red[0][t] + red[1][t] + red[2][t] + red[3][t];
  } else if (bx < 288) {               // ======== q projection ========
    unsigned short (*xb)[136]  = reinterpret_cast<unsigned short (*)[136]>(smem);
    unsigned short (*wql)[136] = reinterpret_cast<unsigned short (*)[136]>(smem + 17408);
    const int s0 = (bx - 256) * 64;
    for (int i = t; i < 2048; i += 256) {
      int r = i >> 5, c4 = (i & 31) * 4;
      float4 v = *reinterpret_cast<const float4*>(&x[(s0 + r) * 128 + c4]);
      ushort4 u; u.x = f2b(v.x); u.y = f2b(v.y); u.z = f2b(v.z); u.w = f2b(v.w);
      *reinterpret_cast<ushort4*>(&xb[r][c4]) = u;
    }
    for (int i = t; i < 4096; i += 256) {
      int r = i >> 5, c4 = (i & 31) * 4;
      float4 v = *reinterpret_cast<const float4*>(&wq[r * 128 + c4]);
      ushort4 u; u.x = f2b(v.x); u.y = f2b(v.y); u.z = f2b(v.z); u.w = f2b(v.w);
      *reinterpret_cast<ushort4*>(&wql[r][c4]) = u;
    }
    __syncthreads();
    f32x4 acc[8] = {};
    #pragma unroll
    for (int kc = 0; kc < 4; ++kc) {
      s8v a = *reinterpret_cast<const s8v*>(&xb[w*16 + (l&15)][kc*32 + kq]);
      #pragma unroll
      for (int nt = 0; nt < 8; ++nt) {
        s8v b = *reinterpret_cast<const s8v*>(&wql[nt*16 + (l&15)][kc*32 + kq]);
        acc[nt] = MFMA16(a, b, acc[nt]);
      }
    }
    const int r0g = s0 + w * 16 + r0l;
    #pragma unroll
    for (int nt = 0; nt < 8; ++nt) {
      const int col = nt * 16 + (l & 15);
      const float bb = bq[col];
      #pragma unroll
      for (int i = 0; i < 4; ++i)
        qbf[(r0g + i) * 128 + col] = f2b((acc[nt][i] + bb) * SCALE);
    }
  } else {                             // ======== weight conversion ========
    const float* src; unsigned short* dst; int off = 0;
    if (bx == 288)      { src = wk;  dst = wkb; }
    else if (bx == 289) { src = wv;  dst = wvb; }
    else if (bx == 290) { src = wo;  dst = wob; }
    else                { src = wfc; dst = wfcb; off = (bx - 291) * 16384; }
    for (int i = t; i < 4096; i += 256) {
      float4 v = *reinterpret_cast<const float4*>(&src[off + i * 4]);
      ushort4 u; u.x = f2b(v.x); u.y = f2b(v.y); u.z = f2b(v.z); u.w = f2b(v.w);
      *reinterpret_cast<ushort4*>(&dst[off + i * 4]) = u;
    }
  }
}

// ---------------------------------------------------------------------------
// D2 k_p2 (32 blocks): per 16-row m-strip: T = S^T@x (K=2048, pure MFMA loop);
// srow from srowp partials (prologue, latency hidden under GEMM); memn in LDS;
// then k and v projections.
// ---------------------------------------------------------------------------
__global__ __launch_bounds__(256) void k_p2(
    const unsigned short* __restrict__ STb, const unsigned short* __restrict__ xT,
    const float* __restrict__ mem, const float* __restrict__ srowp,
    const unsigned short* __restrict__ wkb, const unsigned short* __restrict__ wvb,
    const float* __restrict__ bk, const float* __restrict__ bv,
    unsigned short* __restrict__ kbf, unsigned short* __restrict__ vT) {
  __shared__ float Tld[16][132];
  __shared__ float srowl[16];
  __shared__ unsigned short mnl[16][136];
  const int t = threadIdx.x;
  const int w = t >> 6, l = t & 63;
  const int kq = (l >> 4) * 8;
  const int r0l = (l >> 4) * 4;
  const int m0 = blockIdx.x * 16;

  if (t < 16) {                        // srow reduce (overlaps with GEMM)
    float s = 0.f;
    #pragma unroll
    for (int c = 0; c < 32; ++c) s += srowp[c * 512 + m0 + t];
    srowl[t] = s;
  }
  f32x4 acc[2] = {};
  const int arow = m0 + (l & 15);
  #pragma unroll 4
  for (int kk = 0; kk < 64; ++kk) {    // pure loads + MFMA
    s8v a = *reinterpret_cast<const s8v*>(&STb[arow * 2048 + kk * 32 + kq]);
    #pragma unroll
    for (int nt = 0; nt < 2; ++nt) {
      s8v b = *reinterpret_cast<const s8v*>(&xT[(w*32 + nt*16 + (l&15)) * 2048 + kk*32 + kq]);
      acc[nt] = MFMA16(a, b, acc[nt]);
    }
  }
  #pragma unroll
  for (int nt = 0; nt < 2; ++nt) {
    const int col = w * 32 + nt * 16 + (l & 15);
    #pragma unroll
    for (int i = 0; i < 4; ++i) Tld[r0l + i][col] = acc[nt][i];
  }
  __syncthreads();
  #pragma unroll
  for (int i = 0; i < 8; ++i) {        // memn strip (bf16, LDS only)
    const int flat = t + 256 * i;
    const int r = flat >> 7, c = flat & 127;
    const float mv = mem[(m0 + r) * 128 + c];
    mnl[r][c] = f2b(mv + LRC * (Tld[r][c] - srowl[r] * mv));
  }
  __syncthreads();
  #pragma unroll
  for (int p = 0; p < 2; ++p) {        // p=0: k, p=1: v
    const unsigned short* W = p ? wvb : wkb;
    const float* bias = p ? bv : bk;
    f32x4 pacc[2] = {};
    #pragma unroll
    for (int kc = 0; kc < 4; ++kc) {
      s8v a = *reinterpret_cast<const s8v*>(&mnl[l & 15][kc * 32 + kq]);
      #pragma unroll
      for (int nt = 0; nt < 2; ++nt) {
        s8v b = *reinterpret_cast<const s8v*>(&W[(w*32 + nt*16 + (l&15)) * 128 + kc*32 + kq]);
        pacc[nt] = MFMA16(a, b, pacc[nt]);
      }
    }
    #pragma unroll
    for (int nt = 0; nt < 2; ++nt) {
      const int col = w * 32 + nt * 16 + (l & 15);
      const float bb = bias[col];
      if (p == 0) {
        #pragma unroll
        for (int i = 0; i < 4; ++i)
          kbf[(m0 + r0l + i) * 128 + col] = f2b(pacc[nt][i] + bb);
      } else {
        ushort4 u;
        u.x = f2b(pacc[nt][0] + bb); u.y = f2b(pacc[nt][1] + bb);
        u.z = f2b(pacc[nt][2] + bb); u.w = f2b(pacc[nt][3] + bb);
        *reinterpret_cast<ushort4*>(&vT[col * 512 + m0 + r0l]) = u;
      }
    }
  }
}

// ---------------------------------------------------------------------------
// D3 k_p3 (128 blocks): per 16 query rows, end-to-end:
//  scores+softmax (reg) -> P LDS -> PV -> ctx LDS -> wo -> attno LDS -> fc+relu
// ---------------------------------------------------------------------------
__global__ __launch_bounds__(256) void k_p3(
    const unsigned short* __restrict__ qbf, const unsigned short* __restrict__ kbf,
    const unsigned short* __restrict__ vT, const unsigned short* __restrict__ wob,
    const unsigned short* __restrict__ wfcb, const float* __restrict__ bo,
    const float* __restrict__ bfc, float* __restrict__ out) {
  __shared__ alignas(16) char smem[75264];
  unsigned short (*Pl)[520] = reinterpret_cast<unsigned short (*)[520]>(smem);
  unsigned short (*cl)[136] = reinterpret_cast<unsigned short (*)[136]>(smem + 66560);
  unsigned short (*al)[136] = reinterpret_cast<unsigned short (*)[136]>(smem + 70912);
  const int t = threadIdx.x;
  const int w = t >> 6, l = t & 63;
  const int kq = (l >> 4) * 8;
  const int r0l = (l >> 4) * 4;
  const int r0 = blockIdx.x * 16;      // 16 query rows (bs index)

  {                                    // -- phase A: scores + softmax, head w --
    const int h = w;
    const s8v a = *reinterpret_cast<const s8v*>(&qbf[(r0 + (l & 15)) * 128 + h * 32 + kq]);
    f32x4 acc[32];
    #pragma unroll
    for (int mt = 0; mt < 32; ++mt) acc[mt] = f32x4{0.f, 0.f, 0.f, 0.f};
    #pragma unroll
    for (int mt = 0; mt < 32; ++mt) {
      s8v b2 = *reinterpret_cast<const s8v*>(&kbf[(mt*16 + (l&15)) * 128 + h*32 + kq]);
      acc[mt] = MFMA16(a, b2, acc[mt]);
    }
    #pragma unroll
    for (int i = 0; i < 4; ++i) {
      float mx = acc[0][i];
      #pragma unroll
      for (int mt = 1; mt < 32; ++mt) mx = fmaxf(mx, acc[mt][i]);
      mx = fmaxf(mx, __shfl_xor(mx, 1));
      mx = fmaxf(mx, __shfl_xor(mx, 2));
      mx = fmaxf(mx, __shfl_xor(mx, 4));
      mx = fmaxf(mx, __shfl_xor(mx, 8));
      float sm = 0.f;
      #pragma unroll
      for (int mt = 0; mt < 32; ++mt) {
        float e = __expf(acc[mt][i] - mx); acc[mt][i] = e; sm += e;
      }
      sm += __shfl_xor(sm, 1); sm += __shfl_xor(sm, 2);
      sm += __shfl_xor(sm, 4); sm += __shfl_xor(sm, 8);
      const float inv = 1.f / sm;
      #pragma unroll
      for (int mt = 0; mt < 32; ++mt)
        Pl[h * 16 + r0l + i][mt * 16 + (l & 15)] = f2b(acc[mt][i] * inv);
    }
  }
  __syncthreads();
  {                                    // -- phase B: PV, head w --
    const int h = w;
    f32x4 acc[2] = {};
    #pragma unroll 4
    for (int kk = 0; kk < 16; ++kk) {
      s8v a = *reinterpret_cast<const s8v*>(&Pl[h * 16 + (l & 15)][kk * 32 + kq]);
      #pragma unroll
      for (int nt = 0; nt < 2; ++nt) {
        s8v b2 = *reinterpret_cast<const s8v*>(&vT[(h*32 + nt*16 + (l&15)) * 512 + kk*32 + kq]);
        acc[nt] = MFMA16(a, b2, acc[nt]);
      }
    }
    #pragma unroll
    for (int nt = 0; nt < 2; ++nt) {
      const int col = h * 32 + nt * 16 + (l & 15);
      #pragma unroll
      for (int i = 0; i < 4; ++i) cl[r0l + i][col] = f2b(acc[nt][i]);
    }
  }
  __syncthreads();
  {                                    // -- phase C: attno = ctx@wo^T + bo --
    f32x4 acc[2] = {};
    #pragma unroll
    for (int kc = 0; kc < 4; ++kc) {
      s8v a = *reinterpret_cast<const s8v*>(&cl[l & 15][kc * 32 + kq]);
      #pragma unroll
      for (int nt = 0; nt < 2; ++nt) {
        s8v b2 = *reinterpret_cast<const s8v*>(&wob[(w*32 + nt*16 + (l&15)) * 128 + kc*32 + kq]);
        acc[nt] = MFMA16(a, b2, acc[nt]);
      }
    }
    #pragma unroll
    for (int nt = 0; nt < 2; ++nt) {
      const int col = w * 32 + nt * 16 + (l & 15);
      const float bb = bo[col];
      #pragma unroll
      for (int i = 0; i < 4; ++i) al[r0l + i][col] = f2b(acc[nt][i] + bb);
    }
  }
  __syncthreads();
  {                                    // -- phase D: out = relu(attno@wfc^T + bfc) --
    f32x4 acc[8] = {};
    #pragma unroll
    for (int kc = 0; kc < 4; ++kc) {
      s8v a = *reinterpret_cast<const s8v*>(&al[l & 15][kc * 32 + kq]);
      #pragma unroll
      for (int nt = 0; nt < 8; ++nt) {
        s8v b2 = *reinterpret_cast<const s8v*>(&wfcb[(w*128 + nt*16 + (l&15)) * 128 + kc*32 + kq]);
        acc[nt] = MFMA16(a, b2, acc[nt]);
      }
    }
    #pragma unroll
    for (int nt = 0; nt < 8; ++nt) {
      const int col = w * 128 + nt * 16 + (l & 15);
      const float bb = bfc[col];
      #pragma unroll
      for (int i = 0; i < 4; ++i)
        out[(r0 + r0l + i) * 512 + col] = fmaxf(acc[nt][i] + bb, 0.f);
    }
  }
}

// ---------------------------------------------------------------------------
extern "C" void kernel_launch(void* const* d_in, const int* in_sizes, int n_in,
                              void* d_out, int out_size, void* d_ws, size_t ws_size,
                              hipStream_t stream) {
  const float* x    = (const float*)d_in[0];
  const float* mem  = (const float*)d_in[1];
  const float* w_q  = (const float*)d_in[2];
  const float* w_k  = (const float*)d_in[3];
  const float* w_v  = (const float*)d_in[4];
  const float* b_q  = (const float*)d_in[5];
  const float* b_k  = (const float*)d_in[6];
  const float* b_v  = (const float*)d_in[7];
  const float* w_o  = (const float*)d_in[8];
  const float* b_o  = (const float*)d_in[9];
  const float* w_fc = (const float*)d_in[10];
  const float* b_fc = (const float*)d_in[11];
  float* out = (float*)d_out;

  char* base = (char*)d_ws;            // ~3.7 MB total
  unsigned short* STb  = (unsigned short*)(base);             // 2 MB   S^T[m][bs]
  unsigned short* xT   = (unsigned short*)(base + 2097152);   // 512 KB x^T[d][bs]
  unsigned short* qbf  = (unsigned short*)(base + 2621440);   // 512 KB
  unsigned short* kbf  = (unsigned short*)(base + 3145728);   // 128 KB
  unsigned short* vT   = (unsigned short*)(base + 3276800);   // 128 KB v^T[d][m]
  unsigned short* wkb  = (unsigned short*)(base + 3407872);   // 32 KB
  unsigned short* wvb  = (unsigned short*)(base + 3440640);   // 32 KB
  unsigned short* wob  = (unsigned short*)(base + 3473408);   // 32 KB
  unsigned short* wfcb = (unsigned short*)(base + 3506176);   // 128 KB
  float* srowp         = (float*)(base + 3637248);            // 64 KB [32][512]

  k_p1<<<295, 256, 0, stream>>>(x, mem, w_q, w_k, w_v, w_o, w_fc, b_q,
                                STb, xT, qbf, srowp, wkb, wvb, wob, wfcb);
  k_p2<<<32, 256, 0, stream>>>(STb, xT, mem, srowp, wkb, wvb, b_k, b_v, kbf, vT);
  k_p3<<<128, 256, 0, stream>>>(qbf, kbf, vT, wob, wfcb, b_o, b_fc, out);
}

// Round 9
// 64.622 us; speedup vs baseline: 2.3774x; 1.0063x over previous
//
#include <hip/hip_runtime.h>
#include <hip/hip_bf16.h>
#include <math.h>

// Problem constants (fixed by setup_inputs)
#define SS 1024
#define MM 512
#define LRC (0.1f/2048.0f)          // LR / (B*S)
#define SCALE 0.17677669529663687f  // 1/sqrt(32)

typedef __attribute__((ext_vector_type(8))) short s8v;    // 8 bf16 (one MFMA frag)
typedef __attribute__((ext_vector_type(4))) float f32x4;
#define MFMA16(a, b, c) __builtin_amdgcn_mfma_f32_16x16x32_bf16(a, b, c, 0, 0, 0)

__device__ __forceinline__ unsigned short f2b(float f) {   // fp32 -> bf16 RNE
  union { float f; unsigned int u; } v; v.f = f;
  return (unsigned short)((v.u + 0x7FFFu + ((v.u >> 16) & 1u)) >> 16);
}

// ---------------------------------------------------------------------------
// D1 k_p1 (295 blocks): R6 body (coalesced staging) + srowp column-sum epilogue.
//  bx<256   : surprise tile (bs0=(bx&31)*64, m0=(bx>>5)*64)
//  256..287 : q-projection (64 rows each)
//  288..294 : weight conversion wk,wv,wo,wfc -> bf16
// ---------------------------------------------------------------------------
__global__ __launch_bounds__(256) void k_p1(
    const float* __restrict__ x, const float* __restrict__ mem,
    const float* __restrict__ wq, const float* __restrict__ wk,
    const float* __restrict__ wv, const float* __restrict__ wo,
    const float* __restrict__ wfc, const float* __restrict__ bq,
    unsigned short* __restrict__ STb, unsigned short* __restrict__ xT,
    unsigned short* __restrict__ qbf, float* __restrict__ srowp,
    unsigned short* __restrict__ wkb, unsigned short* __restrict__ wvb,
    unsigned short* __restrict__ wob, unsigned short* __restrict__ wfcb) {
  __shared__ alignas(16) char smem[70400];
  const int t = threadIdx.x, bx = blockIdx.x;
  const int w = t >> 6, l = t & 63;
  const int kq = (l >> 4) * 8;
  const int r0l = (l >> 4) * 4;

  if (bx < 256) {                      // ======== surprise tiles ========
    float (*xl)[132]          = reinterpret_cast<float (*)[132]>(smem);
    unsigned short (*xb)[136] = reinterpret_cast<unsigned short (*)[136]>(smem + 33792);
    unsigned short (*mb)[136] = reinterpret_cast<unsigned short (*)[136]>(smem + 51200);
    float* xn                 = reinterpret_cast<float*>(smem + 68608);
    float* mn                 = reinterpret_cast<float*>(smem + 68864);
    float (*red)[64]          = reinterpret_cast<float (*)[64]>(smem + 69120);
    const int bs0 = (bx & 31) * 64, m0 = (bx >> 5) * 64;

    for (int i = t; i < 2048; i += 256) {          // stage x tile (fp32 + bf16)
      int r = i >> 5, c4 = (i & 31) * 4;
      float4 v = *reinterpret_cast<const float4*>(&x[(bs0 + r) * 128 + c4]);
      xl[r][c4] = v.x; xl[r][c4+1] = v.y; xl[r][c4+2] = v.z; xl[r][c4+3] = v.w;
      ushort4 u; u.x = f2b(v.x); u.y = f2b(v.y); u.z = f2b(v.z); u.w = f2b(v.w);
      *reinterpret_cast<ushort4*>(&xb[r][c4]) = u;
    }
    __syncthreads();
    {                                              // xnorm (fp32)
      int r = t >> 2, q = t & 3;
      float s = 0.f;
      #pragma unroll
      for (int j = 0; j < 32; ++j) { float v = xl[r][q * 32 + j]; s += v * v; }
      s += __shfl_xor(s, 1); s += __shfl_xor(s, 2);
      if (q == 0) xn[r] = s;
    }
    if ((bx >> 5) == 0) {                          // emit xT for P2
      int d = t >> 1, hh = t & 1;
      #pragma unroll
      for (int j4 = 0; j4 < 32; j4 += 4) {
        ushort4 u;
        u.x = xb[hh*32 + j4    ][d];
        u.y = xb[hh*32 + j4 + 1][d];
        u.z = xb[hh*32 + j4 + 2][d];
        u.w = xb[hh*32 + j4 + 3][d];
        *reinterpret_cast<ushort4*>(&xT[d * 2048 + bs0 + hh*32 + j4]) = u;
      }
    }
    __syncthreads();                               // xl free -> reuse for mem
    for (int i = t; i < 2048; i += 256) {
      int r = i >> 5, c4 = (i & 31) * 4;
      float4 v = *reinterpret_cast<const float4*>(&mem[(m0 + r) * 128 + c4]);
      xl[r][c4] = v.x; xl[r][c4+1] = v.y; xl[r][c4+2] = v.z; xl[r][c4+3] = v.w;
      ushort4 u; u.x = f2b(v.x); u.y = f2b(v.y); u.z = f2b(v.z); u.w = f2b(v.w);
      *reinterpret_cast<ushort4*>(&mb[r][c4]) = u;
    }
    __syncthreads();
    {                                              // mnorm (fp32)
      int r = t >> 2, q = t & 3;
      float s = 0.f;
      #pragma unroll
      for (int j = 0; j < 32; ++j) { float v = xl[r][q * 32 + j]; s += v * v; }
      s += __shfl_xor(s, 1); s += __shfl_xor(s, 2);
      if (q == 0) mn[r] = s;
    }
    __syncthreads();
    f32x4 acc[4] = {};                             // G = x@mem^T
    #pragma unroll
    for (int kc = 0; kc < 4; ++kc) {
      s8v a = *reinterpret_cast<const s8v*>(&xb[w*16 + (l&15)][kc*32 + kq]);
      #pragma unroll
      for (int mt = 0; mt < 4; ++mt) {
        s8v b = *reinterpret_cast<const s8v*>(&mb[mt*16 + (l&15)][kc*32 + kq]);
        acc[mt] = MFMA16(a, b, acc[mt]);
      }
    }
    const int r0g = bs0 + w * 16 + r0l;
    float xnr[4];
    #pragma unroll
    for (int i = 0; i < 4; ++i) xnr[i] = xn[w*16 + r0l + i];
    #pragma unroll
    for (int mt = 0; mt < 4; ++mt) {
      const int coll = mt * 16 + (l & 15);
      const float mnv = mn[coll];
      const float s0 = sqrtf(fmaxf(0.f, xnr[0] + mnv - 2.f * acc[mt][0]));
      const float s1 = sqrtf(fmaxf(0.f, xnr[1] + mnv - 2.f * acc[mt][1]));
      const float s2 = sqrtf(fmaxf(0.f, xnr[2] + mnv - 2.f * acc[mt][2]));
      const float s3 = sqrtf(fmaxf(0.f, xnr[3] + mnv - 2.f * acc[mt][3]));
      ushort4 u; u.x = f2b(s0); u.y = f2b(s1); u.z = f2b(s2); u.w = f2b(s3);
      *reinterpret_cast<ushort4*>(&STb[(m0 + coll) * 2048 + r0g]) = u;
      float cs = s0 + s1 + s2 + s3;    // column partial over this wave's 16 rows
      cs += __shfl_xor(cs, 16); cs += __shfl_xor(cs, 32);
      if (l < 16) red[w][mt*16 + l] = cs;
    }
    __syncthreads();
    if (t < 64)                        // per-tile column sums -> srowp
      srowp[(bx & 31) * 512 + m0 + t] =
          red[0][t] + red[1][t] + red[2][t] + red[3][t];
  } else if (bx < 288) {               // ======== q projection ========
    unsigned short (*xb)[136]  = reinterpret_cast<unsigned short (*)[136]>(smem);
    unsigned short (*wql)[136] = reinterpret_cast<unsigned short (*)[136]>(smem + 17408);
    const int s0 = (bx - 256) * 64;
    for (int i = t; i < 2048; i += 256) {
      int r = i >> 5, c4 = (i & 31) * 4;
      float4 v = *reinterpret_cast<const float4*>(&x[(s0 + r) * 128 + c4]);
      ushort4 u; u.x = f2b(v.x); u.y = f2b(v.y); u.z = f2b(v.z); u.w = f2b(v.w);
      *reinterpret_cast<ushort4*>(&xb[r][c4]) = u;
    }
    for (int i = t; i < 4096; i += 256) {
      int r = i >> 5, c4 = (i & 31) * 4;
      float4 v = *reinterpret_cast<const float4*>(&wq[r * 128 + c4]);
      ushort4 u; u.x = f2b(v.x); u.y = f2b(v.y); u.z = f2b(v.z); u.w = f2b(v.w);
      *reinterpret_cast<ushort4*>(&wql[r][c4]) = u;
    }
    __syncthreads();
    f32x4 acc[8] = {};
    #pragma unroll
    for (int kc = 0; kc < 4; ++kc) {
      s8v a = *reinterpret_cast<const s8v*>(&xb[w*16 + (l&15)][kc*32 + kq]);
      #pragma unroll
      for (int nt = 0; nt < 8; ++nt) {
        s8v b = *reinterpret_cast<const s8v*>(&wql[nt*16 + (l&15)][kc*32 + kq]);
        acc[nt] = MFMA16(a, b, acc[nt]);
      }
    }
    const int r0g = s0 + w * 16 + r0l;
    #pragma unroll
    for (int nt = 0; nt < 8; ++nt) {
      const int col = nt * 16 + (l & 15);
      const float bb = bq[col];
      #pragma unroll
      for (int i = 0; i < 4; ++i)
        qbf[(r0g + i) * 128 + col] = f2b((acc[nt][i] + bb) * SCALE);
    }
  } else {                             // ======== weight conversion ========
    const float* src; unsigned short* dst; int off = 0;
    if (bx == 288)      { src = wk;  dst = wkb; }
    else if (bx == 289) { src = wv;  dst = wvb; }
    else if (bx == 290) { src = wo;  dst = wob; }
    else                { src = wfc; dst = wfcb; off = (bx - 291) * 16384; }
    for (int i = t; i < 4096; i += 256) {
      float4 v = *reinterpret_cast<const float4*>(&src[off + i * 4]);
      ushort4 u; u.x = f2b(v.x); u.y = f2b(v.y); u.z = f2b(v.z); u.w = f2b(v.w);
      *reinterpret_cast<ushort4*>(&dst[off + i * 4]) = u;
    }
  }
}

// ---------------------------------------------------------------------------
// D2 k_p2 (32 blocks): per 16-row m-strip: T = S^T@x (K=2048, pure loads+MFMA);
// srow from srowp partials (prologue, hidden under GEMM); memn in LDS;
// then k and v projections.
// ---------------------------------------------------------------------------
__global__ __launch_bounds__(256) void k_p2(
    const unsigned short* __restrict__ STb, const unsigned short* __restrict__ xT,
    const float* __restrict__ mem, const float* __restrict__ srowp,
    const unsigned short* __restrict__ wkb, const unsigned short* __restrict__ wvb,
    const float* __restrict__ bk, const float* __restrict__ bv,
    unsigned short* __restrict__ kbf, unsigned short* __restrict__ vT) {
  __shared__ float Tld[16][132];
  __shared__ float srowl[16];
  __shared__ unsigned short mnl[16][136];
  const int t = threadIdx.x;
  const int w = t >> 6, l = t & 63;
  const int kq = (l >> 4) * 8;
  const int r0l = (l >> 4) * 4;
  const int m0 = blockIdx.x * 16;

  if (t < 16) {                        // srow reduce (overlaps with GEMM)
    float s = 0.f;
    #pragma unroll
    for (int c = 0; c < 32; ++c) s += srowp[c * 512 + m0 + t];
    srowl[t] = s;
  }
  f32x4 acc[2] = {};
  const int arow = m0 + (l & 15);
  #pragma unroll 4
  for (int kk = 0; kk < 64; ++kk) {    // pure loads + MFMA
    s8v a = *reinterpret_cast<const s8v*>(&STb[arow * 2048 + kk * 32 + kq]);
    #pragma unroll
    for (int nt = 0; nt < 2; ++nt) {
      s8v b = *reinterpret_cast<const s8v*>(&xT[(w*32 + nt*16 + (l&15)) * 2048 + kk*32 + kq]);
      acc[nt] = MFMA16(a, b, acc[nt]);
    }
  }
  #pragma unroll
  for (int nt = 0; nt < 2; ++nt) {
    const int col = w * 32 + nt * 16 + (l & 15);
    #pragma unroll
    for (int i = 0; i < 4; ++i) Tld[r0l + i][col] = acc[nt][i];
  }
  __syncthreads();
  #pragma unroll
  for (int i = 0; i < 8; ++i) {        // memn strip (bf16, LDS only)
    const int flat = t + 256 * i;
    const int r = flat >> 7, c = flat & 127;
    const float mv = mem[(m0 + r) * 128 + c];
    mnl[r][c] = f2b(mv + LRC * (Tld[r][c] - srowl[r] * mv));
  }
  __syncthreads();
  #pragma unroll
  for (int p = 0; p < 2; ++p) {        // p=0: k, p=1: v
    const unsigned short* W = p ? wvb : wkb;
    const float* bias = p ? bv : bk;
    f32x4 pacc[2] = {};
    #pragma unroll
    for (int kc = 0; kc < 4; ++kc) {
      s8v a = *reinterpret_cast<const s8v*>(&mnl[l & 15][kc * 32 + kq]);
      #pragma unroll
      for (int nt = 0; nt < 2; ++nt) {
        s8v b = *reinterpret_cast<const s8v*>(&W[(w*32 + nt*16 + (l&15)) * 128 + kc*32 + kq]);
        pacc[nt] = MFMA16(a, b, pacc[nt]);
      }
    }
    #pragma unroll
    for (int nt = 0; nt < 2; ++nt) {
      const int col = w * 32 + nt * 16 + (l & 15);
      const float bb = bias[col];
      if (p == 0) {
        #pragma unroll
        for (int i = 0; i < 4; ++i)
          kbf[(m0 + r0l + i) * 128 + col] = f2b(pacc[nt][i] + bb);
      } else {
        ushort4 u;
        u.x = f2b(pacc[nt][0] + bb); u.y = f2b(pacc[nt][1] + bb);
        u.z = f2b(pacc[nt][2] + bb); u.w = f2b(pacc[nt][3] + bb);
        *reinterpret_cast<ushort4*>(&vT[col * 512 + m0 + r0l]) = u;
      }
    }
  }
}

// ---------------------------------------------------------------------------
// D3 k_p3 (128 blocks): per 16 query rows, end-to-end (unchanged from R6):
//  scores+softmax (reg) -> P LDS -> PV -> ctx LDS -> wo -> attno LDS -> fc+relu
// ---------------------------------------------------------------------------
__global__ __launch_bounds__(256) void k_p3(
    const unsigned short* __restrict__ qbf, const unsigned short* __restrict__ kbf,
    const unsigned short* __restrict__ vT, const unsigned short* __restrict__ wob,
    const unsigned short* __restrict__ wfcb, const float* __restrict__ bo,
    const float* __restrict__ bfc, float* __restrict__ out) {
  __shared__ alignas(16) char smem[75264];
  unsigned short (*Pl)[520] = reinterpret_cast<unsigned short (*)[520]>(smem);
  unsigned short (*cl)[136] = reinterpret_cast<unsigned short (*)[136]>(smem + 66560);
  unsigned short (*al)[136] = reinterpret_cast<unsigned short (*)[136]>(smem + 70912);
  const int t = threadIdx.x;
  const int w = t >> 6, l = t & 63;
  const int kq = (l >> 4) * 8;
  const int r0l = (l >> 4) * 4;
  const int r0 = blockIdx.x * 16;      // 16 query rows (bs index)

  {                                    // -- phase A: scores + softmax, head w --
    const int h = w;
    const s8v a = *reinterpret_cast<const s8v*>(&qbf[(r0 + (l & 15)) * 128 + h * 32 + kq]);
    f32x4 acc[32];
    #pragma unroll
    for (int mt = 0; mt < 32; ++mt) acc[mt] = f32x4{0.f, 0.f, 0.f, 0.f};
    #pragma unroll
    for (int mt = 0; mt < 32; ++mt) {
      s8v b2 = *reinterpret_cast<const s8v*>(&kbf[(mt*16 + (l&15)) * 128 + h*32 + kq]);
      acc[mt] = MFMA16(a, b2, acc[mt]);
    }
    #pragma unroll
    for (int i = 0; i < 4; ++i) {
      float mx = acc[0][i];
      #pragma unroll
      for (int mt = 1; mt < 32; ++mt) mx = fmaxf(mx, acc[mt][i]);
      mx = fmaxf(mx, __shfl_xor(mx, 1));
      mx = fmaxf(mx, __shfl_xor(mx, 2));
      mx = fmaxf(mx, __shfl_xor(mx, 4));
      mx = fmaxf(mx, __shfl_xor(mx, 8));
      float sm = 0.f;
      #pragma unroll
      for (int mt = 0; mt < 32; ++mt) {
        float e = __expf(acc[mt][i] - mx); acc[mt][i] = e; sm += e;
      }
      sm += __shfl_xor(sm, 1); sm += __shfl_xor(sm, 2);
      sm += __shfl_xor(sm, 4); sm += __shfl_xor(sm, 8);
      const float inv = 1.f / sm;
      #pragma unroll
      for (int mt = 0; mt < 32; ++mt)
        Pl[h * 16 + r0l + i][mt * 16 + (l & 15)] = f2b(acc[mt][i] * inv);
    }
  }
  __syncthreads();
  {                                    // -- phase B: PV, head w --
    const int h = w;
    f32x4 acc[2] = {};
    #pragma unroll 4
    for (int kk = 0; kk < 16; ++kk) {
      s8v a = *reinterpret_cast<const s8v*>(&Pl[h * 16 + (l & 15)][kk * 32 + kq]);
      #pragma unroll
      for (int nt = 0; nt < 2; ++nt) {
        s8v b2 = *reinterpret_cast<const s8v*>(&vT[(h*32 + nt*16 + (l&15)) * 512 + kk*32 + kq]);
        acc[nt] = MFMA16(a, b2, acc[nt]);
      }
    }
    #pragma unroll
    for (int nt = 0; nt < 2; ++nt) {
      const int col = h * 32 + nt * 16 + (l & 15);
      #pragma unroll
      for (int i = 0; i < 4; ++i) cl[r0l + i][col] = f2b(acc[nt][i]);
    }
  }
  __syncthreads();
  {                                    // -- phase C: attno = ctx@wo^T + bo --
    f32x4 acc[2] = {};
    #pragma unroll
    for (int kc = 0; kc < 4; ++kc) {
      s8v a = *reinterpret_cast<const s8v*>(&cl[l & 15][kc * 32 + kq]);
      #pragma unroll
      for (int nt = 0; nt < 2; ++nt) {
        s8v b2 = *reinterpret_cast<const s8v*>(&wob[(w*32 + nt*16 + (l&15)) * 128 + kc*32 + kq]);
        acc[nt] = MFMA16(a, b2, acc[nt]);
      }
    }
    #pragma unroll
    for (int nt = 0; nt < 2; ++nt) {
      const int col = w * 32 + nt * 16 + (l & 15);
      const float bb = bo[col];
      #pragma unroll
      for (int i = 0; i < 4; ++i) al[r0l + i][col] = f2b(acc[nt][i] + bb);
    }
  }
  __syncthreads();
  {                                    // -- phase D: out = relu(attno@wfc^T + bfc) --
    f32x4 acc[8] = {};
    #pragma unroll
    for (int kc = 0; kc < 4; ++kc) {
      s8v a = *reinterpret_cast<const s8v*>(&al[l & 15][kc * 32 + kq]);
      #pragma unroll
      for (int nt = 0; nt < 8; ++nt) {
        s8v b2 = *reinterpret_cast<const s8v*>(&wfcb[(w*128 + nt*16 + (l&15)) * 128 + kc*32 + kq]);
        acc[nt] = MFMA16(a, b2, acc[nt]);
      }
    }
    #pragma unroll
    for (int nt = 0; nt < 8; ++nt) {
      const int col = w * 128 + nt * 16 + (l & 15);
      const float bb = bfc[col];
      #pragma unroll
      for (int i = 0; i < 4; ++i)
        out[(r0 + r0l + i) * 512 + col] = fmaxf(acc[nt][i] + bb, 0.f);
    }
  }
}

// ---------------------------------------------------------------------------
extern "C" void kernel_launch(void* const* d_in, const int* in_sizes, int n_in,
                              void* d_out, int out_size, void* d_ws, size_t ws_size,
                              hipStream_t stream) {
  const float* x    = (const float*)d_in[0];
  const float* mem  = (const float*)d_in[1];
  const float* w_q  = (const float*)d_in[2];
  const float* w_k  = (const float*)d_in[3];
  const float* w_v  = (const float*)d_in[4];
  const float* b_q  = (const float*)d_in[5];
  const float* b_k  = (const float*)d_in[6];
  const float* b_v  = (const float*)d_in[7];
  const float* w_o  = (const float*)d_in[8];
  const float* b_o  = (const float*)d_in[9];
  const float* w_fc = (const float*)d_in[10];
  const float* b_fc = (const float*)d_in[11];
  float* out = (float*)d_out;

  char* base = (char*)d_ws;            // ~3.7 MB total
  unsigned short* STb  = (unsigned short*)(base);             // 2 MB   S^T[m][bs]
  unsigned short* xT   = (unsigned short*)(base + 2097152);   // 512 KB x^T[d][bs]
  unsigned short* qbf  = (unsigned short*)(base + 2621440);   // 512 KB
  unsigned short* kbf  = (unsigned short*)(base + 3145728);   // 128 KB
  unsigned short* vT   = (unsigned short*)(base + 3276800);   // 128 KB v^T[d][m]
  unsigned short* wkb  = (unsigned short*)(base + 3407872);   // 32 KB
  unsigned short* wvb  = (unsigned short*)(base + 3440640);   // 32 KB
  unsigned short* wob  = (unsigned short*)(base + 3473408);   // 32 KB
  unsigned short* wfcb = (unsigned short*)(base + 3506176);   // 128 KB
  float* srowp         = (float*)(base + 3637248);            // 64 KB [32][512]

  k_p1<<<295, 256, 0, stream>>>(x, mem, w_q, w_k, w_v, w_o, w_fc, b_q,
                                STb, xT, qbf, srowp, wkb, wvb, wob, wfcb);
  k_p2<<<32, 256, 0, stream>>>(STb, xT, mem, srowp, wkb, wvb, b_k, b_v, kbf, vT);
  k_p3<<<128, 256, 0, stream>>>(qbf, kbf, vT, wob, wfcb, b_o, b_fc, out);
}

// Round 10
// 58.788 us; speedup vs baseline: 2.6134x; 1.0993x over previous
//
#include <hip/hip_runtime.h>
#include <hip/hip_bf16.h>
#include <math.h>

// Problem constants (fixed by setup_inputs)
#define SS 1024
#define MM 512
#define LRC (0.1f/2048.0f)          // LR / (B*S)
#define SCALE 0.17677669529663687f  // 1/sqrt(32)

typedef __attribute__((ext_vector_type(8))) short s8v;    // 8 bf16 (one MFMA frag)
typedef __attribute__((ext_vector_type(4))) float f32x4;
#define MFMA16(a, b, c) __builtin_amdgcn_mfma_f32_16x16x32_bf16(a, b, c, 0, 0, 0)

__device__ __forceinline__ unsigned short f2b(float f) {   // fp32 -> bf16 RNE
  union { float f; unsigned int u; } v; v.f = f;
  return (unsigned short)((v.u + 0x7FFFu + ((v.u >> 16) & 1u)) >> 16);
}

// ---------------------------------------------------------------------------
// D1 k_p1 (295 blocks):
//  bx<256   : surprise tile (bs0=(bx&31)*64, m0=(bx>>5)*64): self-stage x,mem
//             fp32->LDS(bf16+norms); MFMA G=x@mem^T; S=sqrt(xn+mn-2G);
//             write STb[m][bs] bf16. m-row-0 blocks also emit xT[d][bs].
//  256..287 : q-projection (64 rows each): q=(x@wq^T+bq)*SCALE
//  288..294 : weight conversion wk,wv,wo,wfc -> bf16
// ---------------------------------------------------------------------------
__global__ __launch_bounds__(256) void k_p1(
    const float* __restrict__ x, const float* __restrict__ mem,
    const float* __restrict__ wq, const float* __restrict__ wk,
    const float* __restrict__ wv, const float* __restrict__ wo,
    const float* __restrict__ wfc, const float* __restrict__ bq,
    unsigned short* __restrict__ STb, unsigned short* __restrict__ xT,
    unsigned short* __restrict__ qbf,
    unsigned short* __restrict__ wkb, unsigned short* __restrict__ wvb,
    unsigned short* __restrict__ wob, unsigned short* __restrict__ wfcb) {
  __shared__ alignas(16) char smem[69376];
  const int t = threadIdx.x, bx = blockIdx.x;
  const int w = t >> 6, l = t & 63;
  const int kq = (l >> 4) * 8;
  const int r0l = (l >> 4) * 4;

  if (bx < 256) {                      // ======== surprise tiles ========
    float (*xl)[132]          = reinterpret_cast<float (*)[132]>(smem);
    unsigned short (*xb)[136] = reinterpret_cast<unsigned short (*)[136]>(smem + 33792);
    unsigned short (*mb)[136] = reinterpret_cast<unsigned short (*)[136]>(smem + 51200);
    float* xn                 = reinterpret_cast<float*>(smem + 68608);
    float* mn                 = reinterpret_cast<float*>(smem + 68864);
    const int bs0 = (bx & 31) * 64, m0 = (bx >> 5) * 64;

    for (int i = t; i < 2048; i += 256) {          // stage x tile (fp32 + bf16)
      int r = i >> 5, c4 = (i & 31) * 4;
      float4 v = *reinterpret_cast<const float4*>(&x[(bs0 + r) * 128 + c4]);
      xl[r][c4] = v.x; xl[r][c4+1] = v.y; xl[r][c4+2] = v.z; xl[r][c4+3] = v.w;
      ushort4 u; u.x = f2b(v.x); u.y = f2b(v.y); u.z = f2b(v.z); u.w = f2b(v.w);
      *reinterpret_cast<ushort4*>(&xb[r][c4]) = u;
    }
    __syncthreads();
    {                                              // xnorm (fp32)
      int r = t >> 2, q = t & 3;
      float s = 0.f;
      #pragma unroll
      for (int j = 0; j < 32; ++j) { float v = xl[r][q * 32 + j]; s += v * v; }
      s += __shfl_xor(s, 1); s += __shfl_xor(s, 2);
      if (q == 0) xn[r] = s;
    }
    if ((bx >> 5) == 0) {                          // emit xT for P2
      int d = t >> 1, hh = t & 1;
      #pragma unroll
      for (int j4 = 0; j4 < 32; j4 += 4) {
        ushort4 u;
        u.x = xb[hh*32 + j4    ][d];
        u.y = xb[hh*32 + j4 + 1][d];
        u.z = xb[hh*32 + j4 + 2][d];
        u.w = xb[hh*32 + j4 + 3][d];
        *reinterpret_cast<ushort4*>(&xT[d * 2048 + bs0 + hh*32 + j4]) = u;
      }
    }
    __syncthreads();                               // xl free -> reuse for mem
    for (int i = t; i < 2048; i += 256) {
      int r = i >> 5, c4 = (i & 31) * 4;
      float4 v = *reinterpret_cast<const float4*>(&mem[(m0 + r) * 128 + c4]);
      xl[r][c4] = v.x; xl[r][c4+1] = v.y; xl[r][c4+2] = v.z; xl[r][c4+3] = v.w;
      ushort4 u; u.x = f2b(v.x); u.y = f2b(v.y); u.z = f2b(v.z); u.w = f2b(v.w);
      *reinterpret_cast<ushort4*>(&mb[r][c4]) = u;
    }
    __syncthreads();
    {                                              // mnorm (fp32)
      int r = t >> 2, q = t & 3;
      float s = 0.f;
      #pragma unroll
      for (int j = 0; j < 32; ++j) { float v = xl[r][q * 32 + j]; s += v * v; }
      s += __shfl_xor(s, 1); s += __shfl_xor(s, 2);
      if (q == 0) mn[r] = s;
    }
    __syncthreads();
    f32x4 acc[4] = {};                             // G = x@mem^T
    #pragma unroll
    for (int kc = 0; kc < 4; ++kc) {
      s8v a = *reinterpret_cast<const s8v*>(&xb[w*16 + (l&15)][kc*32 + kq]);
      #pragma unroll
      for (int mt = 0; mt < 4; ++mt) {
        s8v b = *reinterpret_cast<const s8v*>(&mb[mt*16 + (l&15)][kc*32 + kq]);
        acc[mt] = MFMA16(a, b, acc[mt]);
      }
    }
    const int r0g = bs0 + w * 16 + r0l;
    float xnr[4];
    #pragma unroll
    for (int i = 0; i < 4; ++i) xnr[i] = xn[w*16 + r0l + i];
    #pragma unroll
    for (int mt = 0; mt < 4; ++mt) {
      const int coll = mt * 16 + (l & 15);
      const float mnv = mn[coll];
      ushort4 u;
      u.x = f2b(sqrtf(fmaxf(0.f, xnr[0] + mnv - 2.f * acc[mt][0])));
      u.y = f2b(sqrtf(fmaxf(0.f, xnr[1] + mnv - 2.f * acc[mt][1])));
      u.z = f2b(sqrtf(fmaxf(0.f, xnr[2] + mnv - 2.f * acc[mt][2])));
      u.w = f2b(sqrtf(fmaxf(0.f, xnr[3] + mnv - 2.f * acc[mt][3])));
      *reinterpret_cast<ushort4*>(&STb[(m0 + coll) * 2048 + r0g]) = u;
    }
  } else if (bx < 288) {               // ======== q projection ========
    unsigned short (*xb)[136]  = reinterpret_cast<unsigned short (*)[136]>(smem);
    unsigned short (*wql)[136] = reinterpret_cast<unsigned short (*)[136]>(smem + 17408);
    const int s0 = (bx - 256) * 64;
    for (int i = t; i < 2048; i += 256) {
      int r = i >> 5, c4 = (i & 31) * 4;
      float4 v = *reinterpret_cast<const float4*>(&x[(s0 + r) * 128 + c4]);
      ushort4 u; u.x = f2b(v.x); u.y = f2b(v.y); u.z = f2b(v.z); u.w = f2b(v.w);
      *reinterpret_cast<ushort4*>(&xb[r][c4]) = u;
    }
    for (int i = t; i < 4096; i += 256) {
      int r = i >> 5, c4 = (i & 31) * 4;
      float4 v = *reinterpret_cast<const float4*>(&wq[r * 128 + c4]);
      ushort4 u; u.x = f2b(v.x); u.y = f2b(v.y); u.z = f2b(v.z); u.w = f2b(v.w);
      *reinterpret_cast<ushort4*>(&wql[r][c4]) = u;
    }
    __syncthreads();
    f32x4 acc[8] = {};
    #pragma unroll
    for (int kc = 0; kc < 4; ++kc) {
      s8v a = *reinterpret_cast<const s8v*>(&xb[w*16 + (l&15)][kc*32 + kq]);
      #pragma unroll
      for (int nt = 0; nt < 8; ++nt) {
        s8v b = *reinterpret_cast<const s8v*>(&wql[nt*16 + (l&15)][kc*32 + kq]);
        acc[nt] = MFMA16(a, b, acc[nt]);
      }
    }
    const int r0g = s0 + w * 16 + r0l;
    #pragma unroll
    for (int nt = 0; nt < 8; ++nt) {
      const int col = nt * 16 + (l & 15);
      const float bb = bq[col];
      #pragma unroll
      for (int i = 0; i < 4; ++i)
        qbf[(r0g + i) * 128 + col] = f2b((acc[nt][i] + bb) * SCALE);
    }
  } else {                             // ======== weight conversion ========
    const float* src; unsigned short* dst; int off = 0;
    if (bx == 288)      { src = wk;  dst = wkb; }
    else if (bx == 289) { src = wv;  dst = wvb; }
    else if (bx == 290) { src = wo;  dst = wob; }
    else                { src = wfc; dst = wfcb; off = (bx - 291) * 16384; }
    for (int i = t; i < 4096; i += 256) {
      float4 v = *reinterpret_cast<const float4*>(&src[off + i * 4]);
      ushort4 u; u.x = f2b(v.x); u.y = f2b(v.y); u.z = f2b(v.z); u.w = f2b(v.w);
      *reinterpret_cast<ushort4*>(&dst[off + i * 4]) = u;
    }
  }
}

// ---------------------------------------------------------------------------
// D2 k_p2 (32 blocks): per 16-row m-strip: T = S^T@x (K=2048, MFMA) with srow
// free from streamed S frags; memn in LDS; then k and v projections.
// ---------------------------------------------------------------------------
__global__ __launch_bounds__(256) void k_p2(
    const unsigned short* __restrict__ STb, const unsigned short* __restrict__ xT,
    const float* __restrict__ mem,
    const unsigned short* __restrict__ wkb, const unsigned short* __restrict__ wvb,
    const float* __restrict__ bk, const float* __restrict__ bv,
    unsigned short* __restrict__ kbf, unsigned short* __restrict__ vT) {
  __shared__ float Tld[16][132];
  __shared__ float srowl[16];
  __shared__ unsigned short mnl[16][136];
  const int t = threadIdx.x;
  const int w = t >> 6, l = t & 63;
  const int kq = (l >> 4) * 8;
  const int r0l = (l >> 4) * 4;
  const int m0 = blockIdx.x * 16;

  f32x4 acc[2] = {};
  float ssum = 0.f;
  const int arow = m0 + (l & 15);
  #pragma unroll 4
  for (int kk = 0; kk < 64; ++kk) {
    s8v a = *reinterpret_cast<const s8v*>(&STb[arow * 2048 + kk * 32 + kq]);
    #pragma unroll
    for (int j = 0; j < 8; ++j) {      // srow partial from streamed S values
      union { unsigned int u; float f; } cv;
      cv.u = ((unsigned int)(unsigned short)a[j]) << 16;
      ssum += cv.f;
    }
    #pragma unroll
    for (int nt = 0; nt < 2; ++nt) {
      s8v b = *reinterpret_cast<const s8v*>(&xT[(w*32 + nt*16 + (l&15)) * 2048 + kk*32 + kq]);
      acc[nt] = MFMA16(a, b, acc[nt]);
    }
  }
  ssum += __shfl_xor(ssum, 16); ssum += __shfl_xor(ssum, 32);
  if (w == 0 && l < 16) srowl[l] = ssum;
  #pragma unroll
  for (int nt = 0; nt < 2; ++nt) {
    const int col = w * 32 + nt * 16 + (l & 15);
    #pragma unroll
    for (int i = 0; i < 4; ++i) Tld[r0l + i][col] = acc[nt][i];
  }
  __syncthreads();
  #pragma unroll
  for (int i = 0; i < 8; ++i) {        // memn strip (bf16, LDS only)
    const int flat = t + 256 * i;
    const int r = flat >> 7, c = flat & 127;
    const float mv = mem[(m0 + r) * 128 + c];
    mnl[r][c] = f2b(mv + LRC * (Tld[r][c] - srowl[r] * mv));
  }
  __syncthreads();
  #pragma unroll
  for (int p = 0; p < 2; ++p) {        // p=0: k, p=1: v
    const unsigned short* W = p ? wvb : wkb;
    const float* bias = p ? bv : bk;
    f32x4 pacc[2] = {};
    #pragma unroll
    for (int kc = 0; kc < 4; ++kc) {
      s8v a = *reinterpret_cast<const s8v*>(&mnl[l & 15][kc * 32 + kq]);
      #pragma unroll
      for (int nt = 0; nt < 2; ++nt) {
        s8v b = *reinterpret_cast<const s8v*>(&W[(w*32 + nt*16 + (l&15)) * 128 + kc*32 + kq]);
        pacc[nt] = MFMA16(a, b, pacc[nt]);
      }
    }
    #pragma unroll
    for (int nt = 0; nt < 2; ++nt) {
      const int col = w * 32 + nt * 16 + (l & 15);
      const float bb = bias[col];
      if (p == 0) {
        #pragma unroll
        for (int i = 0; i < 4; ++i)
          kbf[(m0 + r0l + i) * 128 + col] = f2b(pacc[nt][i] + bb);
      } else {
        ushort4 u;
        u.x = f2b(pacc[nt][0] + bb); u.y = f2b(pacc[nt][1] + bb);
        u.z = f2b(pacc[nt][2] + bb); u.w = f2b(pacc[nt][3] + bb);
        *reinterpret_cast<ushort4*>(&vT[col * 512 + m0 + r0l]) = u;
      }
    }
  }
}

// ---------------------------------------------------------------------------
// D3 k_p3 (128 blocks): per 16 query rows, end-to-end:
//  scores+softmax (reg) -> P LDS -> PV -> ctx LDS -> wo -> attno LDS -> fc+relu
// ---------------------------------------------------------------------------
__global__ __launch_bounds__(256) void k_p3(
    const unsigned short* __restrict__ qbf, const unsigned short* __restrict__ kbf,
    const unsigned short* __restrict__ vT, const unsigned short* __restrict__ wob,
    const unsigned short* __restrict__ wfcb, const float* __restrict__ bo,
    const float* __restrict__ bfc, float* __restrict__ out) {
  __shared__ alignas(16) char smem[75264];
  unsigned short (*Pl)[520] = reinterpret_cast<unsigned short (*)[520]>(smem);
  unsigned short (*cl)[136] = reinterpret_cast<unsigned short (*)[136]>(smem + 66560);
  unsigned short (*al)[136] = reinterpret_cast<unsigned short (*)[136]>(smem + 70912);
  const int t = threadIdx.x;
  const int w = t >> 6, l = t & 63;
  const int kq = (l >> 4) * 8;
  const int r0l = (l >> 4) * 4;
  const int r0 = blockIdx.x * 16;      // 16 query rows (bs index)

  {                                    // -- phase A: scores + softmax, head w --
    const int h = w;
    const s8v a = *reinterpret_cast<const s8v*>(&qbf[(r0 + (l & 15)) * 128 + h * 32 + kq]);
    f32x4 acc[32];
    #pragma unroll
    for (int mt = 0; mt < 32; ++mt) acc[mt] = f32x4{0.f, 0.f, 0.f, 0.f};
    #pragma unroll
    for (int mt = 0; mt < 32; ++mt) {
      s8v b2 = *reinterpret_cast<const s8v*>(&kbf[(mt*16 + (l&15)) * 128 + h*32 + kq]);
      acc[mt] = MFMA16(a, b2, acc[mt]);
    }
    #pragma unroll
    for (int i = 0; i < 4; ++i) {
      float mx = acc[0][i];
      #pragma unroll
      for (int mt = 1; mt < 32; ++mt) mx = fmaxf(mx, acc[mt][i]);
      mx = fmaxf(mx, __shfl_xor(mx, 1));
      mx = fmaxf(mx, __shfl_xor(mx, 2));
      mx = fmaxf(mx, __shfl_xor(mx, 4));
      mx = fmaxf(mx, __shfl_xor(mx, 8));
      float sm = 0.f;
      #pragma unroll
      for (int mt = 0; mt < 32; ++mt) {
        float e = __expf(acc[mt][i] - mx); acc[mt][i] = e; sm += e;
      }
      sm += __shfl_xor(sm, 1); sm += __shfl_xor(sm, 2);
      sm += __shfl_xor(sm, 4); sm += __shfl_xor(sm, 8);
      const float inv = 1.f / sm;
      #pragma unroll
      for (int mt = 0; mt < 32; ++mt)
        Pl[h * 16 + r0l + i][mt * 16 + (l & 15)] = f2b(acc[mt][i] * inv);
    }
  }
  __syncthreads();
  {                                    // -- phase B: PV, head w --
    const int h = w;
    f32x4 acc[2] = {};
    #pragma unroll 4
    for (int kk = 0; kk < 16; ++kk) {
      s8v a = *reinterpret_cast<const s8v*>(&Pl[h * 16 + (l & 15)][kk * 32 + kq]);
      #pragma unroll
      for (int nt = 0; nt < 2; ++nt) {
        s8v b2 = *reinterpret_cast<const s8v*>(&vT[(h*32 + nt*16 + (l&15)) * 512 + kk*32 + kq]);
        acc[nt] = MFMA16(a, b2, acc[nt]);
      }
    }
    #pragma unroll
    for (int nt = 0; nt < 2; ++nt) {
      const int col = h * 32 + nt * 16 + (l & 15);
      #pragma unroll
      for (int i = 0; i < 4; ++i) cl[r0l + i][col] = f2b(acc[nt][i]);
    }
  }
  __syncthreads();
  {                                    // -- phase C: attno = ctx@wo^T + bo --
    f32x4 acc[2] = {};
    #pragma unroll
    for (int kc = 0; kc < 4; ++kc) {
      s8v a = *reinterpret_cast<const s8v*>(&cl[l & 15][kc * 32 + kq]);
      #pragma unroll
      for (int nt = 0; nt < 2; ++nt) {
        s8v b2 = *reinterpret_cast<const s8v*>(&wob[(w*32 + nt*16 + (l&15)) * 128 + kc*32 + kq]);
        acc[nt] = MFMA16(a, b2, acc[nt]);
      }
    }
    #pragma unroll
    for (int nt = 0; nt < 2; ++nt) {
      const int col = w * 32 + nt * 16 + (l & 15);
      const float bb = bo[col];
      #pragma unroll
      for (int i = 0; i < 4; ++i) al[r0l + i][col] = f2b(acc[nt][i] + bb);
    }
  }
  __syncthreads();
  {                                    // -- phase D: out = relu(attno@wfc^T + bfc) --
    f32x4 acc[8] = {};
    #pragma unroll
    for (int kc = 0; kc < 4; ++kc) {
      s8v a = *reinterpret_cast<const s8v*>(&al[l & 15][kc * 32 + kq]);
      #pragma unroll
      for (int nt = 0; nt < 8; ++nt) {
        s8v b2 = *reinterpret_cast<const s8v*>(&wfcb[(w*128 + nt*16 + (l&15)) * 128 + kc*32 + kq]);
        acc[nt] = MFMA16(a, b2, acc[nt]);
      }
    }
    #pragma unroll
    for (int nt = 0; nt < 8; ++nt) {
      const int col = w * 128 + nt * 16 + (l & 15);
      const float bb = bfc[col];
      #pragma unroll
      for (int i = 0; i < 4; ++i)
        out[(r0 + r0l + i) * 512 + col] = fmaxf(acc[nt][i] + bb, 0.f);
    }
  }
}

// ---------------------------------------------------------------------------
extern "C" void kernel_launch(void* const* d_in, const int* in_sizes, int n_in,
                              void* d_out, int out_size, void* d_ws, size_t ws_size,
                              hipStream_t stream) {
  const float* x    = (const float*)d_in[0];
  const float* mem  = (const float*)d_in[1];
  const float* w_q  = (const float*)d_in[2];
  const float* w_k  = (const float*)d_in[3];
  const float* w_v  = (const float*)d_in[4];
  const float* b_q  = (const float*)d_in[5];
  const float* b_k  = (const float*)d_in[6];
  const float* b_v  = (const float*)d_in[7];
  const float* w_o  = (const float*)d_in[8];
  const float* b_o  = (const float*)d_in[9];
  const float* w_fc = (const float*)d_in[10];
  const float* b_fc = (const float*)d_in[11];
  float* out = (float*)d_out;

  char* base = (char*)d_ws;            // ~3.64 MB total
  unsigned short* STb  = (unsigned short*)(base);             // 2 MB   S^T[m][bs]
  unsigned short* xT   = (unsigned short*)(base + 2097152);   // 512 KB x^T[d][bs]
  unsigned short* qbf  = (unsigned short*)(base + 2621440);   // 512 KB
  unsigned short* kbf  = (unsigned short*)(base + 3145728);   // 128 KB
  unsigned short* vT   = (unsigned short*)(base + 3276800);   // 128 KB v^T[d][m]
  unsigned short* wkb  = (unsigned short*)(base + 3407872);   // 32 KB
  unsigned short* wvb  = (unsigned short*)(base + 3440640);   // 32 KB
  unsigned short* wob  = (unsigned short*)(base + 3473408);   // 32 KB
  unsigned short* wfcb = (unsigned short*)(base + 3506176);   // 128 KB

  k_p1<<<295, 256, 0, stream>>>(x, mem, w_q, w_k, w_v, w_o, w_fc, b_q,
                                STb, xT, qbf, wkb, wvb, wob, wfcb);
  k_p2<<<32, 256, 0, stream>>>(STb, xT, mem, wkb, wvb, b_k, b_v, kbf, vT);
  k_p3<<<128, 256, 0, stream>>>(qbf, kbf, vT, wob, wfcb, b_o, b_fc, out);
}